// Round 9
// baseline (183.963 us; speedup 1.0000x reference)
//
#include <hip/hip_runtime.h>
#include <hip/hip_bf16.h>

// LSTM: SEQ=64, IN=100000, H=50 (4H=200 gates)
// x[64,100000] f32, Wi[100000,200] f32, bi[200], Wh[50,200], bh[200] -> h[50]
//
// R16: k1 occupancy fix. R15's ledger: k1 ~48us vs 16-20us HBM floor with
//      BOTH util counters low -> latency/occupancy-bound. 92KB dbuf pinned
//      k1 to 1 block/CU; every barrier convoyed all 8 waves (collective
//      bubble, nothing to fill it — why R8/R9/R13 source pipelining all
//      nulled). Now: 512 blocks x 256 threads, single 45KB LDS buffer ->
//      2 INDEPENDENT blocks/CU; when one blocks at barrier/vmcnt the other
//      computes. Dual-regset 2-deep prefetch kept; lgkm-only barriers
//      (2/tile, single buffer needs both). 4 waves: wave=gset, each does
//      both s-tiles (acc[2][2]=64 AGPR, ~190 VGPR, cap via
//      __launch_bounds__(256,2)).
// K2: adapted to 512 partials (each slice sums 16).
// K3: frozen R15 (gate-type-per-wave, 50 wt/lane, 1 lgkm barrier/step).

#define K_DIM 100000
#define NG 200
#define NS 64
#define TK 32                    // 100000 = 32 * 3125 exactly
#define NBLK 512
#define NTILES 3125              // K_DIM / TK
#define CELLS (NS * NG)          // 12800
#define CELLS4 (CELLS / 4)       // 3200
#define ROWU 40                  // u16 per LDS row = 32 k + 8 pad = 80 B (16B-aligned)

typedef unsigned short u16;
typedef unsigned int   u32;
typedef __bf16 bf16x8 __attribute__((ext_vector_type(8)));
typedef float  f32x16 __attribute__((ext_vector_type(16)));

// raw workgroup barrier WITHOUT the compiler's vmcnt(0) drain:
// own LDS ops retired (lgkmcnt covers ds_read+ds_write), collective via
// s_barrier; sched_barrier(0) stops the compiler hoisting later LDS ops
// above it. Global prefetch loads stay outstanding.
#define TILE_BARRIER() do {                                   \
    asm volatile("s_waitcnt lgkmcnt(0)" ::: "memory");        \
    __builtin_amdgcn_s_barrier();                             \
    __builtin_amdgcn_sched_barrier(0);                        \
} while (0)

static __device__ __forceinline__ u32 rne16(float f) {
    u32 u = __float_as_uint(f);
    return (u + 0x7FFFu + ((u >> 16) & 1u)) >> 16;
}
static __device__ __forceinline__ void split_hl(float f, u32& h, u32& l) {
    u32 u  = __float_as_uint(f);
    u32 hb = u & 0xFFFF0000u;
    h = hb >> 16;
    l = rne16(f - __uint_as_float(hb));   // remainder exact; rne to bf16
}
static __device__ __forceinline__ void split4(float4 v, u32 h[4], u32 l[4]) {
    split_hl(v.x, h[0], l[0]); split_hl(v.y, h[1], l[1]);
    split_hl(v.z, h[2], l[2]); split_hl(v.w, h[3], l[3]);
}
static __device__ __forceinline__ f32x16 mfma_bf(uint4 a, uint4 b, f32x16 c) {
    return __builtin_amdgcn_mfma_f32_32x32x16_bf16(
        __builtin_bit_cast(bf16x8, a), __builtin_bit_cast(bf16x8, b), c, 0, 0, 0);
}
// broadcast lane j's value of v to all lanes (j compile-time; ignores exec)
static __device__ __forceinline__ float rl(float v, int j) {
    return __int_as_float(__builtin_amdgcn_readlane(__float_as_int(v), j));
}

__global__ __launch_bounds__(256, 2) void k1_gemm_partial(
    const float* __restrict__ x, const float* __restrict__ Wi,
    float* __restrict__ partial)
{
    // SINGLE tile buffer: 45 KB -> 2 blocks/CU
    __shared__ __align__(16) u16 WH[224 * ROWU];   // Wi hi, [g][k]  17.9 KB
    __shared__ __align__(16) u16 WL[224 * ROWU];   // Wi lo
    __shared__ __align__(16) u16 XH[64 * ROWU];    // x  hi, [s][k]   5.1 KB
    __shared__ __align__(16) u16 XL[64 * ROWU];    // x  lo

    const int t    = threadIdx.x;        // 0..255
    const int lane = t & 63;
    const int gset = t >> 6;             // wave 0..3 owns g-tiles {2g, 2g+1}
    const int m    = lane & 31;          // MFMA row/col within tile
    const int h    = lane >> 5;          // k-half

    // zero Wi pad rows 200..223 once
    {
        u32* zh = (u32*)&WH[200 * ROWU];
        u32* zl = (u32*)&WL[200 * ROWU];
        for (int i = t; i < 24 * ROWU / 2; i += 256) { zh[i] = 0; zl[i] = 0; }
    }

    // Wi staging: 400 f4-tasks (g4 0..49 x k4 0..7); thread t owns task t
    // (always, t<256<400) and task t+256 (t<144).
    const int g4a = t >> 3,         k4a = t & 7;
    const int g4b = (t + 256) >> 3, k4b = t & 7;   // (t+256)&7 == t&7
    const bool hw2 = (t < 144);
    // x staging: 512 f4-tasks (s 0..63 x k4 0..7); thread owns s and s+32.
    const int xk  = t & 7;
    const int xsA = t >> 3;              // 0..31
    const int xsB = xsA + 32;            // 32..63

    auto do_loads = [&](int ti, float4 (&w0)[4], float4 (&w1)[4],
                        float4& x0, float4& x1) {
        const size_t kt = (size_t)ti * TK;
#pragma unroll
        for (int j = 0; j < 4; ++j)
            w0[j] = *(const float4*)(Wi + (kt + k4a * 4 + j) * NG + g4a * 4);
        if (hw2) {
#pragma unroll
            for (int j = 0; j < 4; ++j)
                w1[j] = *(const float4*)(Wi + (kt + k4b * 4 + j) * NG + g4b * 4);
        }
        x0 = *(const float4*)(x + (size_t)xsA * K_DIM + kt + xk * 4);
        x1 = *(const float4*)(x + (size_t)xsB * K_DIM + kt + xk * 4);
    };
    auto stage_wi = [&](const float4 (&r)[4], int g4, int k4) {
        u32 hw[4][4], lw[4][4];
#pragma unroll
        for (int j = 0; j < 4; ++j) split4(r[j], hw[j], lw[j]);
#pragma unroll
        for (int j2 = 0; j2 < 4; ++j2) {   // transpose: row g=4g4+j2 gets 4 k's
            int off = (4 * g4 + j2) * ROWU + k4 * 4;
            *(uint2*)&WH[off] = make_uint2(hw[0][j2] | (hw[1][j2] << 16),
                                           hw[2][j2] | (hw[3][j2] << 16));
            *(uint2*)&WL[off] = make_uint2(lw[0][j2] | (lw[1][j2] << 16),
                                           lw[2][j2] | (lw[3][j2] << 16));
        }
    };
    auto stage_x = [&](float4 v, int s) {
        u32 hh[4], ll[4];
        split4(v, hh, ll);
        int off = s * ROWU + xk * 4;
        *(uint2*)&XH[off] = make_uint2(hh[0] | (hh[1] << 16), hh[2] | (hh[3] << 16));
        *(uint2*)&XL[off] = make_uint2(ll[0] | (ll[1] << 16), ll[2] | (ll[3] << 16));
    };

    f32x16 acc[2][2];                    // [stile][tt]
#pragma unroll
    for (int st = 0; st < 2; ++st)
#pragma unroll
        for (int tt = 0; tt < 2; ++tt)
#pragma unroll
            for (int r = 0; r < 16; ++r) acc[st][tt][r] = 0.f;

    // fragment LDS offsets (u16 units)
    const int aoff0 = (0 * 32 + m) * ROWU + h * 8;
    const int aoff1 = (1 * 32 + m) * ROWU + h * 8;
    int boff[2];
#pragma unroll
    for (int tt = 0; tt < 2; ++tt) {
        int gt = (gset == 3 && tt == 1) ? 6 : (2 * gset + tt);
        boff[tt] = (gt * 32 + m) * ROWU + h * 8;
    }

    auto mfma_phase = [&]() {
#pragma unroll
        for (int kk = 0; kk < 2; ++kk) {
            uint4 a0h = *(const uint4*)&XH[aoff0 + kk * 16];
            uint4 a0l = *(const uint4*)&XL[aoff0 + kk * 16];
            uint4 a1h = *(const uint4*)&XH[aoff1 + kk * 16];
            uint4 a1l = *(const uint4*)&XL[aoff1 + kk * 16];
#pragma unroll
            for (int tt = 0; tt < 2; ++tt) {
                uint4 bh = *(const uint4*)&WH[boff[tt] + kk * 16];
                uint4 bl = *(const uint4*)&WL[boff[tt] + kk * 16];
                // per-acc order preserved: xh*wh, xh*wl, xl*wh
                acc[0][tt] = mfma_bf(a0h, bh, acc[0][tt]);
                acc[0][tt] = mfma_bf(a0h, bl, acc[0][tt]);
                acc[0][tt] = mfma_bf(a0l, bh, acc[0][tt]);
                acc[1][tt] = mfma_bf(a1h, bh, acc[1][tt]);
                acc[1][tt] = mfma_bf(a1h, bl, acc[1][tt]);
                acc[1][tt] = mfma_bf(a1l, bh, acc[1][tt]);
            }
        }
    };

    // ---- prologue: A<-t0, B<-t0+NBLK (both < 1024 < 3125, no guard) ----
    float4 wA0[4], wA1[4], wB0[4], wB1[4];
    float4 xA0, xA1, xB0, xB1;
    const int ti0 = blockIdx.x;
    do_loads(ti0,        wA0, wA1, xA0, xA1);
    do_loads(ti0 + NBLK, wB0, wB1, xB0, xB1);

    // ---- main loop: stage cur regset (vmcnt waits only its loads; other
    //      set stays in flight), reissue 2 ahead, barrier, mfma, barrier.
    //      Bubbles are filled by the OTHER block on this CU. ----
    int ti = ti0;
    while (ti < NTILES) {
        {   // consume regset A (tile ti)
            stage_wi(wA0, g4a, k4a);
            if (hw2) stage_wi(wA1, g4b, k4b);
            stage_x(xA0, xsA); stage_x(xA1, xsB);
            int tf = ti + 2 * NBLK;
            if (tf < NTILES) do_loads(tf, wA0, wA1, xA0, xA1);
            TILE_BARRIER();              // stage visible
            mfma_phase();
            TILE_BARRIER();              // readers done; next stage may overwrite
            ti += NBLK;
        }
        if (ti >= NTILES) break;
        {   // consume regset B (tile ti)
            stage_wi(wB0, g4a, k4a);
            if (hw2) stage_wi(wB1, g4b, k4b);
            stage_x(xB0, xsA); stage_x(xB1, xsB);
            int tf = ti + 2 * NBLK;
            if (tf < NTILES) do_loads(tf, wB0, wB1, xB0, xB1);
            TILE_BARRIER();
            mfma_phase();
            TILE_BARRIER();
            ti += NBLK;
        }
    }

    // epilogue: partial[b][s][g]; C/D: col=lane&31, row=(r&3)+8(r>>2)+4h
    float* base = partial + (size_t)blockIdx.x * CELLS;
#pragma unroll
    for (int st = 0; st < 2; ++st) {
#pragma unroll
        for (int tt = 0; tt < 2; ++tt) {
            if (gset == 3 && tt == 1) continue;   // duplicate of tile 6
            int g = (2 * gset + tt) * 32 + m;
            if (g < NG) {
#pragma unroll
                for (int r = 0; r < 16; ++r) {
                    int srow = st * 32 + (r & 3) + 8 * (r >> 2) + 4 * h;
                    base[srow * NG + g] = acc[st][tt][r];
                }
            }
        }
    }
}

__global__ __launch_bounds__(512) void k2_reduce(
    const float* __restrict__ partial, const float* __restrict__ bi,
    const float* __restrict__ bh, float* __restrict__ gates)
{
    __shared__ float4 red[512];
    const int tid   = threadIdx.x;
    const int fid   = tid & 15;                 // f4-cell within block
    const int slice = tid >> 4;                 // 0..31, each sums 16 b's
    const int g4    = blockIdx.x * 16 + fid;    // 0..3199

    const float4* p4 = (const float4*)partial;
    float4 sum = make_float4(0.f, 0.f, 0.f, 0.f);
#pragma unroll 4
    for (int b = slice * 16; b < slice * 16 + 16; ++b) {
        float4 v = p4[(size_t)b * CELLS4 + g4];
        sum.x += v.x; sum.y += v.y; sum.z += v.z; sum.w += v.w;
    }
    red[tid] = sum;
    __syncthreads();
    if (tid < 16) {
        float4 tot = red[tid];
#pragma unroll
        for (int p = 1; p < 32; ++p) {
            float4 v = red[p * 16 + tid];
            tot.x += v.x; tot.y += v.y; tot.z += v.z; tot.w += v.w;
        }
        int gg = (g4 * 4) % NG;                 // NG%4==0: never wraps mid-f4
        float4 b1 = *(const float4*)(bi + gg);
        float4 b2 = *(const float4*)(bh + gg);
        tot.x += b1.x + b2.x; tot.y += b1.y + b2.y;
        tot.z += b1.z + b2.z; tot.w += b1.w + b2.w;
        ((float4*)gates)[g4] = tot;
    }
}

__global__ __launch_bounds__(256)
__attribute__((amdgpu_waves_per_eu(1)))
void k3_lstm(
    const float* __restrict__ gates, const float* __restrict__ Wh,
    float* __restrict__ out)
{
    // 4 waves; wave w = gate type (0=i,1=f,2=g,3=o); lane l<50 = cell l.
    // 50 weights/lane in registers (R15: proven fast, frozen).
    __shared__ float act[2][NG];    // double-buffered by step parity
    const int tid = threadIdx.x;
    const int w   = tid >> 6;       // gate type
    const int l   = tid & 63;
    const bool al = (l < 50);
    const int  lc = al ? l : 49;    // idle lanes compute harmlessly on cell 49
    const int  gidx = w * 50 + lc;  // gate index in [0,200)

    float wv[50];                   // Wh column for this gate: Wh[j][gidx]
#pragma unroll
    for (int j = 0; j < 50; ++j) wv[j] = Wh[j * NG + gidx];

    const float* gp = gates + gidx;
    float gz = gp[0];
    float c = 0.f, h = 0.f;

    for (int s = 0; s < 64; ++s) {
        // prefetch next step's pre-activation (L2-hot; TILE_BARRIER does not
        // drain vmcnt, so this stays in flight under the chain + barrier)
        float nz = (s < 63) ? gp[(s + 1) * NG] : 0.f;

        // z: verbatim R0 association — 4 chains by j mod 4, gz seeds a0,
        // tail j=48,49 -> a0,a1, z=(a0+a1)+(a2+a3). h broadcast intra-wave.
        float a0 = gz, a1 = 0.f, a2 = 0.f, a3 = 0.f;
#pragma unroll
        for (int j = 0; j < 48; j += 4) {
            a0 = fmaf(rl(h, j),     wv[j],     a0);
            a1 = fmaf(rl(h, j + 1), wv[j + 1], a1);
            a2 = fmaf(rl(h, j + 2), wv[j + 2], a2);
            a3 = fmaf(rl(h, j + 3), wv[j + 3], a3);
        }
        a0 = fmaf(rl(h, 48), wv[48], a0);
        a1 = fmaf(rl(h, 49), wv[49], a1);
        float z = (a0 + a1) + (a2 + a3);

        // activation: waves 0,1,3 sigmoid; wave 2 tanh (identical exprs to R0)
        float e = __expf(-z);
        float av;
        if (w == 2) { float e2 = e * e; av = (1.f - e2) / (1.f + e2); }
        else        { av = 1.f / (1.f + e); }
        if (al) act[s & 1][gidx] = av;

        TILE_BARRIER();   // act[s&1] published; lgkmcnt-only (prefetch lives).
        // Race-free: next write to act[s&1] is step s+2, behind barrier(s+1);
        // all step-s readers below finish before passing barrier(s+1).

        // redundant identical c/h update in EVERY wave (same inputs ->
        // same bits) -> no second barrier; h stays wave-local for readlane.
        float iv = act[s & 1][lc];
        float fv = act[s & 1][50 + lc];
        float gv = act[s & 1][100 + lc];
        float ov = act[s & 1][150 + lc];
        c = fmaf(fv, c, iv * gv);
        float e2c = __expf(-2.f * c);
        h = ov * (1.f - e2c) / (1.f + e2c);

        gz = nz;
    }
    if (w == 0 && al) out[l] = h;
}

extern "C" void kernel_launch(void* const* d_in, const int* in_sizes, int n_in,
                              void* d_out, int out_size, void* d_ws, size_t ws_size,
                              hipStream_t stream)
{
    const float* x  = (const float*)d_in[0];
    const float* Wi = (const float*)d_in[1];
    const float* bi = (const float*)d_in[2];
    const float* Wh = (const float*)d_in[3];
    const float* bh = (const float*)d_in[4];
    float* out = (float*)d_out;

    float* partial = (float*)d_ws;                    // 512*12800 f32 = 26.2 MB
    float* gates   = partial + (size_t)NBLK * CELLS;  // 12800 f32

    k1_gemm_partial<<<NBLK, 256, 0, stream>>>(x, Wi, partial);
    k2_reduce<<<CELLS4 / 16, 512, 0, stream>>>(partial, bi, bh, gates);
    k3_lstm<<<1, 256, 0, stream>>>(gates, Wh, out);
}